// Round 12
// baseline (284.321 us; speedup 1.0000x reference)
//
#include <hip/hip_runtime.h>

#define KK 32
#define HH 6
#define OO 31
#define EPS 1e-6f
#define PTS_BLK 256              // 256 pts/block; wave = 64 pts x full o via slices
#define V_DW (KK * HH * 32)      // 6144 dwords: V[k][h(6)][o32]

typedef float f32x4 __attribute__((ext_vector_type(4)));

// Sigma-folded, zero-padded W: V[k][h][o32], col o==31 = 0. 24.6 KB, rebuilt
// each launch by the prep kernel (inputs may be re-poisoned between iters).
//   h=0: W0 - (W3+W5)/s2   h=1: -W1/s2 (x g*dy)   h=2: -W2/s2 (x g*dx)
//   h=3: W3/s4 (x g*dy^2)  h=4: W4/s4 (x g*dx*dy) h=5: W5/s4 (x g*dx^2)
__device__ __align__(256) float V_dev[V_DW];

__global__ void hermite_prep_kernel(const float* __restrict__ W,
                                    const float* __restrict__ sigmas)
{
    int j = blockIdx.x * 256 + threadIdx.x;
    if (j >= V_DW) return;
    int k = j / 192;
    int r = j - k * 192;
    int h = r >> 5;
    int o = r & 31;
    float s  = sigmas[k];
    float s2 = s * s;
    float i2 = 1.0f / (s2 + EPS);
    float i4 = 1.0f / (s2 * s2 + EPS);
    float v = 0.0f;
    if (o < OO) {
        const float* Wk = W + k * (HH * OO);
        float w = Wk[h * OO + o];
        if (h == 0)      v = w - i2 * (Wk[3 * OO + o] + Wk[5 * OO + o]);
        else if (h <= 2) v = -i2 * w;
        else             v = i4 * w;
    }
    V_dev[j] = v;
}

// R10 lesson: scalar-broadcast of V is service-rate-limited (L_eff grew
// 600->1360 cyc as D rose; VALU duty capped ~34%). Fix: V in LDS + within-
// wave o-slice so each fetched V-dword feeds 8 FMAs (8 points/lane).
// Layout: lane = (s = lane>>3, q = lane&7): points q+8m (m=0..7), outputs
// [4s, 4s+4). Per k per lane: 6x ds_read_b128 (V[k][h][4s..4s+4], 8 unique
// 16B chunks spanning 128B -> conflict-free, 8-lane broadcast) feeding
// 8 pts x 4 o x 6 h = 192 FMAs. LDS pipe demand 6x12cyc x 12 waves/CU per
// k-layer = well under the VALU window; latency ~120cyc, compiler-pipelined.
// No inline asm anywhere (R8/R9 lesson: SGPR-tuple asm is fragile).
__global__ __launch_bounds__(256, 3) void hermite_fused_kernel(
    const float* __restrict__ mlp,     // [P, OO]
    const float* __restrict__ cd,      // [P, KK, 2]
    const float* __restrict__ gw,      // [P, KK]
    float* __restrict__ out)           // [P, OO]
{
    __shared__ float smem[PTS_BLK * OO];   // 7936 dw = 31744 B; [0,6144) = V

    const int tid = threadIdx.x;

    // Stage V -> LDS (coalesced float4, 6 per thread).
    {
        const f32x4* __restrict__ src = (const f32x4*)V_dev;
        f32x4* dst = (f32x4*)smem;
#pragma unroll
        for (int i = 0; i < 6; ++i)
            dst[i * 256 + tid] = src[i * 256 + tid];
    }
    __syncthreads();

    const int lane = tid & 63;
    const int wv   = tid >> 6;
    const int s    = lane >> 3;            // o-slice: outputs 4s..4s+4
    const int q    = lane & 7;
    const int p0   = blockIdx.x * PTS_BLK + wv * 64 + q;   // point m: p0 + 8m

    float acc[8][4];
#pragma unroll
    for (int m = 0; m < 8; ++m)
#pragma unroll
        for (int o = 0; o < 4; ++o) acc[m][o] = 0.0f;

#pragma unroll 1
    for (int kt4 = 0; kt4 < 8; ++kt4) {    // 4 k per iteration
        f32x4 ga[8];                       // gw staged 4k x 8 pts
#pragma unroll
        for (int m = 0; m < 8; ++m)
            ga[m] = *(const f32x4*)(gw + (size_t)(p0 + 8 * m) * KK + kt4 * 4);

#pragma unroll
        for (int k2 = 0; k2 < 2; ++k2) {   // 2 k per iteration
            f32x4 c[8];                    // cd staged 2k x 8 pts
#pragma unroll
            for (int m = 0; m < 8; ++m)
                c[m] = *(const f32x4*)(cd + (size_t)(p0 + 8 * m) * (KK * 2)
                                       + (kt4 * 2 + k2) * 4);

#pragma unroll
            for (int j2 = 0; j2 < 2; ++j2) {
                const int k = kt4 * 4 + k2 * 2 + j2;
                const float* vb = &smem[k * 192 + s * 4];
                f32x4 v0 = *(const f32x4*)(vb);
                f32x4 v1 = *(const f32x4*)(vb + 32);
                f32x4 v2 = *(const f32x4*)(vb + 64);
                f32x4 v3 = *(const f32x4*)(vb + 96);
                f32x4 v4 = *(const f32x4*)(vb + 128);
                f32x4 v5 = *(const f32x4*)(vb + 160);
#pragma unroll
                for (int m = 0; m < 8; ++m) {
                    float dx = c[m][2 * j2], dy = c[m][2 * j2 + 1];
                    float g  = ga[m][k2 * 2 + j2];
                    float d1 = g * dy, d2 = g * dx;
                    float d3 = d1 * dy, d4 = d1 * dx, d5 = d2 * dx;
#pragma unroll
                    for (int o = 0; o < 4; ++o) {
                        float a = acc[m][o];
                        a = fmaf(g,  v0[o], a);
                        a = fmaf(d1, v1[o], a);
                        a = fmaf(d2, v2[o], a);
                        a = fmaf(d3, v3[o], a);
                        a = fmaf(d4, v4[o], a);
                        a = fmaf(d5, v5[o], a);
                        acc[m][o] = a;
                    }
                }
            }
        }
    }

    // All waves done reading V before overwriting smem with the mix tile.
    __syncthreads();

    // Epilogue transpose: lane holds (pt = wv*64 + q + 8m, o = 4s + o').
    // Write addr = pt*31 + 4s + o' -> bank (-q + 4s + o') mod 32: the 64
    // (q,s) pairs cover each bank exactly 2x = 2-way = free. Guard o==31
    // (slice 7's padded col aliases next point's o=0).
#pragma unroll
    for (int m = 0; m < 8; ++m)
#pragma unroll
        for (int o = 0; o < 4; ++o) {
            int oo = 4 * s + o;
            if (oo < OO)
                smem[(wv * 64 + q + 8 * m) * OO + oo] = acc[m][o];
        }
    __syncthreads();

    // Coalesced float4 mlp*mix -> out (block region = 7936 contiguous dw).
    {
        const size_t blk_dw = (size_t)blockIdx.x * (PTS_BLK * OO);
        const f32x4* __restrict__ mlpv = (const f32x4*)(mlp + blk_dw);
        f32x4* __restrict__ outv = (f32x4*)(out + blk_dw);
        const f32x4* mixv = (const f32x4*)smem;
#pragma unroll 2
        for (int j = tid; j < (PTS_BLK * OO) / 4; j += 256) {
            f32x4 m = __builtin_nontemporal_load(&mlpv[j]);
            f32x4 x = mixv[j];
            f32x4 r = m * x;
            __builtin_nontemporal_store(r, &outv[j]);
        }
    }
}

extern "C" void kernel_launch(void* const* d_in, const int* in_sizes, int n_in,
                              void* d_out, int out_size, void* d_ws, size_t ws_size,
                              hipStream_t stream)
{
    const float* mlp    = (const float*)d_in[0]; // [B,N,O]
    const float* cd     = (const float*)d_in[1]; // [B,N,K,2]
    const float* sigmas = (const float*)d_in[2]; // [K]
    const float* gw     = (const float*)d_in[3]; // [B,N,K]
    const float* W      = (const float*)d_in[4]; // [K,H,O]
    float* out          = (float*)d_out;

    const int P = in_sizes[3] / KK;              // B*N = 262144

    hermite_prep_kernel<<<(V_DW + 255) / 256, 256, 0, stream>>>(W, sigmas);
    hermite_fused_kernel<<<P / PTS_BLK, 256, 0, stream>>>(mlp, cd, gw, out);
}